// Round 11
// baseline (258.869 us; speedup 1.0000x reference)
//
#include <hip/hip_runtime.h>
#include <hip/hip_bf16.h>

// Attn: energies = out_state @ (history @ W.T).T ; softmax rows.
// S2=S1=4096, N=1024. fp32 in/out. bf16 hi/lo GEMM, 3 products
// (Ah.Bh + Al.Bh + Ah.Bl), separate hi/lo arrays (R15: -33% staged bytes).
// R20 post-mortem: 32x32 MFMA null (110 vs 107) -> NOT MFMA-issue-bound.
//   Slab paced by the staging DRAIN: every version drained vmcnt->0 each
//   slab (DMA gets <=2 windows to land). m201 stages the same 64 KB/tile in
//   3300 cyc BECAUSE loads never drain (counted vmcnt, T4). R11's null was
//   missing T3 (no phases); R16's regression confounded (rewrote windows).
// R21: counted never-drain vmcnt ON the proven R20 window body (2-line
//   change). gemm_e: DMA issue already spread w0..w3 (order Ah,Bh,Al,Bl);
//   boundary vmcnt(0)->vmcnt(4) (drains Ah,Bh(t+1) only), new vmcnt(4) at
//   w2 (drains Al,Bl(t) before bl/al reads, leaves Ah,Bh(t+1) in flight).
//   Each DMA now has 4-5 windows of cover. Tail slabs vmcnt(0).
//   gemm_p: same mechanism (issue Ah,Bh,Bl,Al at w0; boundary vmcnt(1),
//   pre-al-read vmcnt(4)). WAR: boundary lgkmcnt(0) kept; DMAs target only
//   the non-current buffer (readers drained one boundary earlier).

typedef __bf16 bf16x8 __attribute__((ext_vector_type(8)));
typedef float f32x4 __attribute__((ext_vector_type(4)));
typedef float f32x16 __attribute__((ext_vector_type(16)));
typedef unsigned short u16x4 __attribute__((ext_vector_type(4)));

__device__ __forceinline__ unsigned short f2bf(float x) {
  unsigned int u = __float_as_uint(x);
  u += 0x7fffu + ((u >> 16) & 1u);   // RNE
  return (unsigned short)(u >> 16);
}
__device__ __forceinline__ float bf2f(unsigned short h) {
  return __uint_as_float(((unsigned int)h) << 16);
}

__device__ __forceinline__ void async_copy_16(void* lds, const void* gsrc) {
  __builtin_amdgcn_global_load_lds(
      (const __attribute__((address_space(1))) void*)gsrc,
      (__attribute__((address_space(3))) void*)lds, 16, 0, 0);
}

__device__ __forceinline__ void barrier_fenced() {
  asm volatile("" ::: "memory");
  __builtin_amdgcn_s_barrier();
  asm volatile("" ::: "memory");
}

// Fused split: fp32 X[rows x 1024] -> Yh, Yl bf16 (hi + residual-lo) for
// history (4096), W (1024), out_state (4096) in one launch (grid 9216).
__global__ __launch_bounds__(256)
void split_all(const float* __restrict__ H, const float* __restrict__ W,
               const float* __restrict__ OS,
               unsigned short* __restrict__ Hh, unsigned short* __restrict__ Hl,
               unsigned short* __restrict__ Wh, unsigned short* __restrict__ Wl,
               unsigned short* __restrict__ Ah, unsigned short* __restrict__ Al) {
  const int b = blockIdx.x;
  const float* X; unsigned short *Yh, *Yl; size_t row;
  if (b < 4096)      { X = H;  Yh = Hh; Yl = Hl; row = b; }
  else if (b < 5120) { X = W;  Yh = Wh; Yl = Wl; row = b - 4096; }
  else               { X = OS; Yh = Ah; Yl = Al; row = b - 5120; }
  const int c4 = threadIdx.x;
  float4 x = ((const float4*)(X + row * 1024))[c4];
  float xs[4] = {x.x, x.y, x.z, x.w};
  u16x4 h, l;
#pragma unroll
  for (int i = 0; i < 4; ++i) {
    unsigned short hh = f2bf(xs[i]);
    h[i] = hh;
    l[i] = f2bf(xs[i] - bf2f(hh));
  }
  ((u16x4*)(Yh + row * 1024))[c4] = h;
  ((u16x4*)(Yl + row * 1024))[c4] = l;
}

// ===================== stage-2: energies (32x32x16 MFMA) ====================
// C[4096,4096] = Ah.Bh^T + Al.Bh^T + Ah.Bl^T, K=1024. 256x256 tile, 8 waves
// (2x4), wave tile 128x64 = 4x2 frags of 32x32. NBUF=2, 6 windows/slab,
// counted never-drain vmcnt: issue {Ah,Bh,Al,Bl}(t+1) at w0..w3; waits
// vmcnt(4) @w2 (drain Al,Bl(t)) and @boundary (drain Ah,Bh(t+1)).
__global__ __launch_bounds__(512, 2)
void gemm_e(const unsigned short* __restrict__ Ah, const unsigned short* __restrict__ Al,
            const unsigned short* __restrict__ Bh, const unsigned short* __restrict__ Bl,
            float* __restrict__ C) {
  constexpr int NTILES = 32;
  __shared__ unsigned short AhS[2][256 * 32];
  __shared__ unsigned short AlS[2][256 * 32];
  __shared__ unsigned short BhS[2][256 * 32];
  __shared__ unsigned short BlS[2][256 * 32];

  const int tid = threadIdx.x;
  const int w = tid >> 6;
  const int lane = tid & 63;
  const int wm = w >> 2, wn = w & 3;
  const int lr = lane & 31;              // row within 32-group
  const int ls = lane >> 5;              // k-segment (8 bf16)

  // XCD swizzle: grid 256 = 8 XCDs x 32; bijective
  const int id = blockIdx.x;
  const int xcd = id & 7;
  const int j = id >> 3;
  const int bm = ((xcd % 4) * 4 + (j % 4)) * 256;
  const int bn = ((xcd / 4) * 8 + (j / 4)) * 256;

  // staging source pointers: wave w owns 32-row group w on each side.
  const unsigned short *pah, *pal, *pbh, *pbl;
  {
    const size_t ra = (size_t)(bm + w * 32 + lr) * 1024 + ls * 8;
    pah = Ah + ra; pal = Al + ra;
    const size_t rb = (size_t)(bn + w * 32 + lr) * 1024 + ls * 8;
    pbh = Bh + rb; pbl = Bl + rb;
  }

  f32x16 acc[4][2] = {};

  auto stageAh = [&](int buf, int t) {
#pragma unroll
    for (int h = 0; h < 2; ++h)
      async_copy_16(&AhS[buf][w * 1024 + h * 512], pah + t * 32 + h * 16);
  };
  auto stageAl = [&](int buf, int t) {
#pragma unroll
    for (int h = 0; h < 2; ++h)
      async_copy_16(&AlS[buf][w * 1024 + h * 512], pal + t * 32 + h * 16);
  };
  auto stageBh = [&](int buf, int t) {
#pragma unroll
    for (int h = 0; h < 2; ++h)
      async_copy_16(&BhS[buf][w * 1024 + h * 512], pbh + t * 32 + h * 16);
  };
  auto stageBl = [&](int buf, int t) {
#pragma unroll
    for (int h = 0; h < 2; ++h)
      async_copy_16(&BlS[buf][w * 1024 + h * 512], pbl + t * 32 + h * 16);
  };
  auto LDAh = [&](int buf, int g, int h) { return *(const bf16x8*)&AhS[buf][g * 1024 + h * 512 + lane * 8]; };
  auto LDAl = [&](int buf, int g, int h) { return *(const bf16x8*)&AlS[buf][g * 1024 + h * 512 + lane * 8]; };
  auto LDBh = [&](int buf, int g, int h) { return *(const bf16x8*)&BhS[buf][g * 1024 + h * 512 + lane * 8]; };
  auto LDBl = [&](int buf, int g, int h) { return *(const bf16x8*)&BlS[buf][g * 1024 + h * 512 + lane * 8]; };

  // prologue: issue slab 0 in steady-state order Ah,Bh,Al,Bl; drain Ah,Bh only.
  stageAh(0, 0); stageBh(0, 0); stageAl(0, 0); stageBl(0, 0);
  asm volatile("s_waitcnt vmcnt(4)" ::: "memory");
  barrier_fenced();

#pragma unroll 1
  for (int t = 0; t < NTILES; ++t) {
    const int buf = t & 1, nb = buf ^ 1;
    const bool st = (t + 1 < NTILES);
    bf16x8 ah[4][2], al[4][2], bh[2][2], bl[2][2];

    // w0 (refill): read ah[0..2) + bh (landed via boundary vmcnt); issue Ah(t+1)
#pragma unroll
    for (int mt = 0; mt < 2; ++mt)
#pragma unroll
      for (int h = 0; h < 2; ++h) ah[mt][h] = LDAh(buf, wm * 4 + mt, h);
#pragma unroll
    for (int nt = 0; nt < 2; ++nt)
#pragma unroll
      for (int h = 0; h < 2; ++h) bh[nt][h] = LDBh(buf, wn * 2 + nt, h);
    if (st) stageAh(nb, t + 1);
    barrier_fenced();

    // w1: read ah[2..4); issue Bh(t+1); MFMA ah[0..2) x bh (8)
#pragma unroll
    for (int mt = 2; mt < 4; ++mt)
#pragma unroll
      for (int h = 0; h < 2; ++h) ah[mt][h] = LDAh(buf, wm * 4 + mt, h);
    if (st) stageBh(nb, t + 1);
    __builtin_amdgcn_s_setprio(1);
#pragma unroll
    for (int h = 0; h < 2; ++h)
#pragma unroll
      for (int mt = 0; mt < 2; ++mt)
#pragma unroll
        for (int nt = 0; nt < 2; ++nt)
          acc[mt][nt] = __builtin_amdgcn_mfma_f32_32x32x16_bf16(ah[mt][h], bh[nt][h], acc[mt][nt], 0, 0, 0);
    __builtin_amdgcn_s_setprio(0);
    barrier_fenced();

    // w2: counted wait -- drain Al(t),Bl(t) (issued @w2/w3 of slab t-1),
    // keep Ah(t+1),Bh(t+1) in flight. Then read bl; issue Al(t+1);
    // MFMA ah[2..4) x bh (8).
    if (st) asm volatile("s_waitcnt vmcnt(4)" ::: "memory");
    else    asm volatile("s_waitcnt vmcnt(0)" ::: "memory");
#pragma unroll
    for (int nt = 0; nt < 2; ++nt)
#pragma unroll
      for (int h = 0; h < 2; ++h) bl[nt][h] = LDBl(buf, wn * 2 + nt, h);
    if (st) stageAl(nb, t + 1);
    __builtin_amdgcn_s_setprio(1);
#pragma unroll
    for (int h = 0; h < 2; ++h)
#pragma unroll
      for (int mt = 2; mt < 4; ++mt)
#pragma unroll
        for (int nt = 0; nt < 2; ++nt)
          acc[mt][nt] = __builtin_amdgcn_mfma_f32_32x32x16_bf16(ah[mt][h], bh[nt][h], acc[mt][nt], 0, 0, 0);
    __builtin_amdgcn_s_setprio(0);
    barrier_fenced();

    // w3: read al[0..2) (Al(t) drained @w2); issue Bl(t+1); MFMA ah[0..2) x bl (8)
#pragma unroll
    for (int mt = 0; mt < 2; ++mt)
#pragma unroll
      for (int h = 0; h < 2; ++h) al[mt][h] = LDAl(buf, wm * 4 + mt, h);
    if (st) stageBl(nb, t + 1);
    __builtin_amdgcn_s_setprio(1);
#pragma unroll
    for (int h = 0; h < 2; ++h)
#pragma unroll
      for (int mt = 0; mt < 2; ++mt)
#pragma unroll
        for (int nt = 0; nt < 2; ++nt)
          acc[mt][nt] = __builtin_amdgcn_mfma_f32_32x32x16_bf16(ah[mt][h], bl[nt][h], acc[mt][nt], 0, 0, 0);
    __builtin_amdgcn_s_setprio(0);
    barrier_fenced();

    // w4: read al[2..4); MFMA ah[2..4) x bl (8)
#pragma unroll
    for (int mt = 2; mt < 4; ++mt)
#pragma unroll
      for (int h = 0; h < 2; ++h) al[mt][h] = LDAl(buf, wm * 4 + mt, h);
    __builtin_amdgcn_s_setprio(1);
#pragma unroll
    for (int h = 0; h < 2; ++h)
#pragma unroll
      for (int mt = 2; mt < 4; ++mt)
#pragma unroll
        for (int nt = 0; nt < 2; ++nt)
          acc[mt][nt] = __builtin_amdgcn_mfma_f32_32x32x16_bf16(ah[mt][h], bl[nt][h], acc[mt][nt], 0, 0, 0);
    __builtin_amdgcn_s_setprio(0);
    barrier_fenced();

    // w5: MFMA al x bh (16)
    __builtin_amdgcn_s_setprio(1);
#pragma unroll
    for (int h = 0; h < 2; ++h)
#pragma unroll
      for (int mt = 0; mt < 4; ++mt)
#pragma unroll
        for (int nt = 0; nt < 2; ++nt)
          acc[mt][nt] = __builtin_amdgcn_mfma_f32_32x32x16_bf16(al[mt][h], bh[nt][h], acc[mt][nt], 0, 0, 0);
    __builtin_amdgcn_s_setprio(0);

    // boundary: counted -- drain Ah,Bh(t+1) (needed @w0 next), keep
    // Al,Bl(t+1) in flight. lgkmcnt(0): our reads of buf done before its
    // DMAs next slab (WAR).
    __builtin_amdgcn_sched_barrier(0);
    if (st) asm volatile("s_waitcnt vmcnt(4) lgkmcnt(0)" ::: "memory");
    else    asm volatile("s_waitcnt vmcnt(0) lgkmcnt(0)" ::: "memory");
    barrier_fenced();
  }

  // Epilogue. 32x32 C/D: col = lane&31, row = (reg&3)+8*(reg>>2)+4*(lane>>5).
  const int cm0 = bm + wm * 128;
  const int cn0 = bn + wn * 64;
#pragma unroll
  for (int mt = 0; mt < 4; ++mt)
#pragma unroll
    for (int nt = 0; nt < 2; ++nt) {
      const int col = cn0 + nt * 32 + lr;
      const int row0 = cm0 + mt * 32 + ls * 4;
#pragma unroll
      for (int reg = 0; reg < 16; ++reg) {
        const int row = row0 + (reg & 3) + 8 * (reg >> 2);
        C[(size_t)row * 4096 + col] = acc[mt][nt][reg];
      }
    }
}

// ==================== stage-1: proj (split-K=2, counted vmcnt) ==============
// Cpart[kh][4096,1024]. 128x128 tile, 8 waves (2x4), wave tile 64x32.
// NBUF=2 -> 64 KB -> 2 blocks/CU. 16 slabs, 2 windows. Counted never-drain:
// issue {Ah,Bh,Bl,Al}(t+1) @w0; boundary vmcnt(1) (drain Ah,Bh,Bl(t+1),
// keep Al); pre-al-read vmcnt(4) (drain Al(t), keep slab t+1's 4).
__global__ __launch_bounds__(512, 2)
void gemm_p(const unsigned short* __restrict__ Ah, const unsigned short* __restrict__ Al,
            const unsigned short* __restrict__ Bh, const unsigned short* __restrict__ Bl,
            float* __restrict__ Cpart) {
  constexpr int MT = 4, NT = 2, NTILES = 16;
  __shared__ unsigned short AhS[2][128 * 32];
  __shared__ unsigned short AlS[2][128 * 32];
  __shared__ unsigned short BhS[2][128 * 32];
  __shared__ unsigned short BlS[2][128 * 32];

  const int tid = threadIdx.x;
  const int w = tid >> 6;
  const int lane = tid & 63;
  const int wm = w >> 2, wn = w & 3;
  const int lr = lane & 15;
  const int ls = lane >> 4;

  const int kh = blockIdx.x >> 8;
  const int rid = blockIdx.x & 255;
  const int xcd = rid & 7;
  const int j = rid >> 3;
  const int bm = ((xcd % 4) * 8 + (j % 8)) * 128;
  const int bn = ((xcd / 4) * 4 + (j / 8)) * 128;
  const int koff = kh * 512;
  float* __restrict__ C = Cpart + (size_t)kh * 4096 * 1024;

  const unsigned short *pah, *pal, *pbh, *pbl;
  {
    const size_t ra = (size_t)(bm + w * 16 + lr) * 1024 + koff + ls * 8;
    pah = Ah + ra; pal = Al + ra;
    const size_t rb = (size_t)(bn + w * 16 + lr) * 1024 + koff + ls * 8;
    pbh = Bh + rb; pbl = Bl + rb;
  }

  f32x4 acc[MT][NT] = {};

  auto stage_all = [&](int buf, int t) {
    async_copy_16(&AhS[buf][w * 512], pah + t * 32);
    async_copy_16(&BhS[buf][w * 512], pbh + t * 32);
    async_copy_16(&BlS[buf][w * 512], pbl + t * 32);
    async_copy_16(&AlS[buf][w * 512], pal + t * 32);
  };
  auto LDAh = [&](int buf, int g) { return *(const bf16x8*)&AhS[buf][g * 512 + ls * 128 + lr * 8]; };
  auto LDAl = [&](int buf, int g) { return *(const bf16x8*)&AlS[buf][g * 512 + ls * 128 + lr * 8]; };
  auto LDBh = [&](int buf, int g) { return *(const bf16x8*)&BhS[buf][g * 512 + ls * 128 + lr * 8]; };
  auto LDBl = [&](int buf, int g) { return *(const bf16x8*)&BlS[buf][g * 512 + ls * 128 + lr * 8]; };

  // prologue: issue slab 0 (order Ah,Bh,Bl,Al); drain Ah,Bh,Bl only.
  stage_all(0, 0);
  asm volatile("s_waitcnt vmcnt(1)" ::: "memory");
  barrier_fenced();

#pragma unroll 1
  for (int t = 0; t < NTILES; ++t) {
    const int buf = t & 1, nb = buf ^ 1;
    const bool st = (t + 1 < NTILES);
    bf16x8 ah[4], al[4], bh[2], bl[2];

    // w0: Ah,Bh,Bl reads (landed via boundary vmcnt(1)); issue slab t+1;
    // 16 MFMA (ah.bh + ah.bl)
#pragma unroll
    for (int mt = 0; mt < 4; ++mt) ah[mt] = LDAh(buf, wm * MT + mt);
#pragma unroll
    for (int nt = 0; nt < 2; ++nt) bh[nt] = LDBh(buf, wn * NT + nt);
#pragma unroll
    for (int nt = 0; nt < 2; ++nt) bl[nt] = LDBl(buf, wn * NT + nt);
    if (st) stage_all(nb, t + 1);
    barrier_fenced();
    asm volatile("s_waitcnt lgkmcnt(0)" ::: "memory");
    __builtin_amdgcn_sched_barrier(0);
    __builtin_amdgcn_s_setprio(1);
#pragma unroll
    for (int mt = 0; mt < 4; ++mt)
#pragma unroll
      for (int nt = 0; nt < 2; ++nt)
        acc[mt][nt] = __builtin_amdgcn_mfma_f32_16x16x32_bf16(ah[mt], bh[nt], acc[mt][nt], 0, 0, 0);
#pragma unroll
    for (int mt = 0; mt < 4; ++mt)
#pragma unroll
      for (int nt = 0; nt < 2; ++nt)
        acc[mt][nt] = __builtin_amdgcn_mfma_f32_16x16x32_bf16(ah[mt], bl[nt], acc[mt][nt], 0, 0, 0);
    __builtin_amdgcn_s_setprio(0);
    __builtin_amdgcn_sched_barrier(0);

    // w1: counted wait -- drain Al(t) (issued @w0 of slab t-1), keep slab
    // t+1's 4 in flight. Then Al reads; 8 MFMA (al.bh).
    if (st) asm volatile("s_waitcnt vmcnt(4)" ::: "memory");
    else    asm volatile("s_waitcnt vmcnt(0)" ::: "memory");
#pragma unroll
    for (int mt = 0; mt < 4; ++mt) al[mt] = LDAl(buf, wm * MT + mt);
    barrier_fenced();
    asm volatile("s_waitcnt lgkmcnt(0)" ::: "memory");
    __builtin_amdgcn_sched_barrier(0);
    __builtin_amdgcn_s_setprio(1);
#pragma unroll
    for (int mt = 0; mt < 4; ++mt)
#pragma unroll
      for (int nt = 0; nt < 2; ++nt)
        acc[mt][nt] = __builtin_amdgcn_mfma_f32_16x16x32_bf16(al[mt], bh[nt], acc[mt][nt], 0, 0, 0);
    __builtin_amdgcn_s_setprio(0);
    __builtin_amdgcn_sched_barrier(0);

    // boundary: drain Ah,Bh,Bl(t+1) (needed @w0 next), keep Al(t+1).
    __builtin_amdgcn_sched_barrier(0);
    if (st) asm volatile("s_waitcnt vmcnt(1) lgkmcnt(0)" ::: "memory");
    else    asm volatile("s_waitcnt vmcnt(0) lgkmcnt(0)" ::: "memory");
    barrier_fenced();
  }

  const int cm0 = bm + wm * 64;
  const int cn0 = bn + wn * 32;
#pragma unroll
  for (int mt = 0; mt < MT; ++mt)
#pragma unroll
    for (int nt = 0; nt < NT; ++nt) {
      const int col = cn0 + nt * 16 + lr;
      const int row0 = cm0 + mt * 16 + ls * 4;
#pragma unroll
      for (int r = 0; r < 4; ++r)
        C[(size_t)(row0 + r) * 1024 + col] = acc[mt][nt][r];
    }
}

// P = Pa + Pb; split hi/lo into Ph, Pl. Row per block.
__global__ __launch_bounds__(256)
void reduce_split(const float* __restrict__ Pa, const float* __restrict__ Pb,
                  unsigned short* __restrict__ Ph, unsigned short* __restrict__ Pl) {
  const size_t row = blockIdx.x;
  const int c4 = threadIdx.x;
  float4 a = ((const float4*)(Pa + row * 1024))[c4];
  float4 b = ((const float4*)(Pb + row * 1024))[c4];
  float s[4] = {a.x + b.x, a.y + b.y, a.z + b.z, a.w + b.w};
  u16x4 h, l;
#pragma unroll
  for (int i = 0; i < 4; ++i) {
    unsigned short hh = f2bf(s[i]);
    h[i] = hh;
    l[i] = f2bf(s[i] - bf2f(hh));
  }
  ((u16x4*)(Ph + row * 1024))[c4] = h;
  ((u16x4*)(Pl + row * 1024))[c4] = l;
}

// In-place row softmax, N=4096, one block per row, 16 floats/thread in regs.
__global__ __launch_bounds__(256)
void softmax_inplace(float* __restrict__ C, int N) {
  float4* r4 = (float4*)(C + (size_t)blockIdx.x * N);
  const int t = threadIdx.x;
  float4 v[4];
  float mx = -3.0e38f;
#pragma unroll
  for (int i = 0; i < 4; ++i) {
    v[i] = r4[t + i * 256];
    mx = fmaxf(mx, fmaxf(fmaxf(v[i].x, v[i].y), fmaxf(v[i].z, v[i].w)));
  }
#pragma unroll
  for (int o = 32; o; o >>= 1) mx = fmaxf(mx, __shfl_xor(mx, o, 64));
  __shared__ float smax[4], ssum[4];
  const int w = t >> 6;
  if ((t & 63) == 0) smax[w] = mx;
  __syncthreads();
  mx = fmaxf(fmaxf(smax[0], smax[1]), fmaxf(smax[2], smax[3]));
  float s = 0.f;
#pragma unroll
  for (int i = 0; i < 4; ++i) {
    v[i].x = __expf(v[i].x - mx);
    v[i].y = __expf(v[i].y - mx);
    v[i].z = __expf(v[i].z - mx);
    v[i].w = __expf(v[i].w - mx);
    s += (v[i].x + v[i].y) + (v[i].z + v[i].w);
  }
#pragma unroll
  for (int o = 32; o; o >>= 1) s += __shfl_xor(s, o, 64);
  if ((t & 63) == 0) ssum[w] = s;
  __syncthreads();
  const float inv = 1.0f / (ssum[0] + ssum[1] + ssum[2] + ssum[3]);
#pragma unroll
  for (int i = 0; i < 4; ++i) {
    v[i].x *= inv; v[i].y *= inv; v[i].z *= inv; v[i].w *= inv;
    r4[t + i * 256] = v[i];
  }
}

extern "C" void kernel_launch(void* const* d_in, const int* in_sizes, int n_in,
                              void* d_out, int out_size, void* d_ws, size_t ws_size,
                              hipStream_t stream) {
  const float* out_state = (const float*)d_in[0];  // [4096,1024]
  const float* history   = (const float*)d_in[1];  // [4096,1024]
  const float* W         = (const float*)d_in[2];  // [1024,1024]
  float* out = (float*)d_out;                      // [4096,4096]

  unsigned short* Hh = (unsigned short*)d_ws;                 // 4096x1024 each
  unsigned short* Hl = Hh + (size_t)4096 * 1024;
  unsigned short* Wh = Hl + (size_t)4096 * 1024;              // 1024x1024
  unsigned short* Wl = Wh + (size_t)1024 * 1024;
  unsigned short* Ah = Wl + (size_t)1024 * 1024;              // 4096x1024
  unsigned short* Al = Ah + (size_t)4096 * 1024;
  unsigned short* Ph = Al + (size_t)4096 * 1024;              // 4096x1024
  unsigned short* Pl = Ph + (size_t)4096 * 1024;
  float* P32 = (float*)(Pl + (size_t)4096 * 1024);            // 2 x 4096x1024 fp32

  split_all<<<9216, 256, 0, stream>>>(history, W, out_state, Hh, Hl, Wh, Wl, Ah, Al);

  // stage-1: split-K=2 proj, counted vmcnt. 512 blocks, 2 blocks/CU.
  gemm_p<<<512, 512, 0, stream>>>(Hh, Hl, Wh, Wl, P32);
  reduce_split<<<4096, 256, 0, stream>>>(P32, P32 + (size_t)4096 * 1024, Ph, Pl);

  // stage-2: energies, 32x32x16 MFMA, counted never-drain vmcnt. 256 blocks.
  gemm_e<<<256, 512, 0, stream>>>(Ah, Al, Ph, Pl, out);

  softmax_inplace<<<4096, 256, 0, stream>>>(out, 4096);
}

// Round 12
// 255.211 us; speedup vs baseline: 1.0143x; 1.0143x over previous
//
#include <hip/hip_runtime.h>
#include <hip/hip_bf16.h>

// Attn: energies = out_state @ (history @ W.T).T ; softmax rows.
// S2=S1=4096, N=1024. fp32 in/out. bf16 hi/lo GEMM, 3 products
// (Ah.Bh + Al.Bh + Ah.Bl), separate hi/lo arrays (R15: -33% staged bytes).
// R21 post-mortem: slab time == serial SUM of parts (MFMA 3100 + reads 2260
//   + barriers + VALU = 8250 measured); reads and MFMA never overlap. R18's
//   source-level read-ahead nulled because the scheduler re-clusters loads
//   next to consumers (never .s-verified). T19 sched_group_barrier exists
//   precisely to pin a deterministic interleave.
// R22 (gemm_e only; gemm_p = R20-exact):
//   (1) defer al x bh (16 MFMA) into NEXT slab's w0 (was a 12-read window
//       with zero MFMA cover). Operands stay in regs across the boundary;
//       only bh needs a copy (bhp). Slab 0 runs deferred MFMAs on zeroed
//       regs (acc += 0) to keep straight-line code (SGB needs one region).
//       Barriers 7 -> 5 per slab.
//   (2) sched_group_barrier interleave per window: w0 4x{3 DS_READ,4 MFMA},
//       w1-w3 4x{1 DS_READ,2 MFMA}. Masks: DS_READ=0x100 MFMA=0x8 VMEM=0x10.

typedef __bf16 bf16x8 __attribute__((ext_vector_type(8)));
typedef float f32x4 __attribute__((ext_vector_type(4)));
typedef float f32x16 __attribute__((ext_vector_type(16)));
typedef unsigned short u16x4 __attribute__((ext_vector_type(4)));

__device__ __forceinline__ unsigned short f2bf(float x) {
  unsigned int u = __float_as_uint(x);
  u += 0x7fffu + ((u >> 16) & 1u);   // RNE
  return (unsigned short)(u >> 16);
}
__device__ __forceinline__ float bf2f(unsigned short h) {
  return __uint_as_float(((unsigned int)h) << 16);
}

__device__ __forceinline__ void async_copy_16(void* lds, const void* gsrc) {
  __builtin_amdgcn_global_load_lds(
      (const __attribute__((address_space(1))) void*)gsrc,
      (__attribute__((address_space(3))) void*)lds, 16, 0, 0);
}

__device__ __forceinline__ void barrier_fenced() {
  asm volatile("" ::: "memory");
  __builtin_amdgcn_s_barrier();
  asm volatile("" ::: "memory");
}

// Fused split: fp32 X[rows x 1024] -> Yh, Yl bf16 (hi + residual-lo) for
// history (4096), W (1024), out_state (4096) in one launch (grid 9216).
__global__ __launch_bounds__(256)
void split_all(const float* __restrict__ H, const float* __restrict__ W,
               const float* __restrict__ OS,
               unsigned short* __restrict__ Hh, unsigned short* __restrict__ Hl,
               unsigned short* __restrict__ Wh, unsigned short* __restrict__ Wl,
               unsigned short* __restrict__ Ah, unsigned short* __restrict__ Al) {
  const int b = blockIdx.x;
  const float* X; unsigned short *Yh, *Yl; size_t row;
  if (b < 4096)      { X = H;  Yh = Hh; Yl = Hl; row = b; }
  else if (b < 5120) { X = W;  Yh = Wh; Yl = Wl; row = b - 4096; }
  else               { X = OS; Yh = Ah; Yl = Al; row = b - 5120; }
  const int c4 = threadIdx.x;
  float4 x = ((const float4*)(X + row * 1024))[c4];
  float xs[4] = {x.x, x.y, x.z, x.w};
  u16x4 h, l;
#pragma unroll
  for (int i = 0; i < 4; ++i) {
    unsigned short hh = f2bf(xs[i]);
    h[i] = hh;
    l[i] = f2bf(xs[i] - bf2f(hh));
  }
  ((u16x4*)(Yh + row * 1024))[c4] = h;
  ((u16x4*)(Yl + row * 1024))[c4] = l;
}

// ===================== stage-2: energies (32x32x16 MFMA) ====================
// C[4096,4096] = Ah.Bh^T + Al.Bh^T + Ah.Bl^T, K=1024. 256x256 tile, 8 waves
// (2x4), wave tile 128x64 = 4x2 frags of 32x32. NBUF=2. 5 windows/slab,
// al x bh deferred one slab (fills refill window), SGB-pinned interleave.
__global__ __launch_bounds__(512, 2)
void gemm_e(const unsigned short* __restrict__ Ah, const unsigned short* __restrict__ Al,
            const unsigned short* __restrict__ Bh, const unsigned short* __restrict__ Bl,
            float* __restrict__ C) {
  constexpr int NTILES = 32;
  __shared__ unsigned short AhS[2][256 * 32];
  __shared__ unsigned short AlS[2][256 * 32];
  __shared__ unsigned short BhS[2][256 * 32];
  __shared__ unsigned short BlS[2][256 * 32];

  const int tid = threadIdx.x;
  const int w = tid >> 6;
  const int lane = tid & 63;
  const int wm = w >> 2, wn = w & 3;
  const int lr = lane & 31;              // row within 32-group
  const int ls = lane >> 5;              // k-segment (8 bf16)

  // XCD swizzle: grid 256 = 8 XCDs x 32; bijective
  const int id = blockIdx.x;
  const int xcd = id & 7;
  const int j = id >> 3;
  const int bm = ((xcd % 4) * 4 + (j % 4)) * 256;
  const int bn = ((xcd / 4) * 8 + (j / 4)) * 256;

  const unsigned short *pah, *pal, *pbh, *pbl;
  {
    const size_t ra = (size_t)(bm + w * 32 + lr) * 1024 + ls * 8;
    pah = Ah + ra; pal = Al + ra;
    const size_t rb = (size_t)(bn + w * 32 + lr) * 1024 + ls * 8;
    pbh = Bh + rb; pbl = Bl + rb;
  }

  f32x16 acc[4][2] = {};

  auto stageAh = [&](int buf, int t) {
#pragma unroll
    for (int h = 0; h < 2; ++h)
      async_copy_16(&AhS[buf][w * 1024 + h * 512], pah + t * 32 + h * 16);
  };
  auto stageAl = [&](int buf, int t) {
#pragma unroll
    for (int h = 0; h < 2; ++h)
      async_copy_16(&AlS[buf][w * 1024 + h * 512], pal + t * 32 + h * 16);
  };
  auto stageBh = [&](int buf, int t) {
#pragma unroll
    for (int h = 0; h < 2; ++h)
      async_copy_16(&BhS[buf][w * 1024 + h * 512], pbh + t * 32 + h * 16);
  };
  auto stageBl = [&](int buf, int t) {
#pragma unroll
    for (int h = 0; h < 2; ++h)
      async_copy_16(&BlS[buf][w * 1024 + h * 512], pbl + t * 32 + h * 16);
  };
  auto LDAh = [&](int buf, int g, int h) { return *(const bf16x8*)&AhS[buf][g * 1024 + h * 512 + lane * 8]; };
  auto LDAl = [&](int buf, int g, int h) { return *(const bf16x8*)&AlS[buf][g * 1024 + h * 512 + lane * 8]; };
  auto LDBh = [&](int buf, int g, int h) { return *(const bf16x8*)&BhS[buf][g * 1024 + h * 512 + lane * 8]; };
  auto LDBl = [&](int buf, int g, int h) { return *(const bf16x8*)&BlS[buf][g * 1024 + h * 512 + lane * 8]; };

  // fragment registers live across slabs (al/bhp feed the deferred product).
  bf16x8 ah[4][2], bh[2][2], bl[2][2];
  bf16x8 al[4][2] = {};                  // zeros: slab-0 deferred MFMA adds 0
  bf16x8 bhp[2][2] = {};

  // prologue: stage slab 0, full drain, publish.
  stageAh(0, 0); stageBh(0, 0); stageAl(0, 0); stageBl(0, 0);
  asm volatile("s_waitcnt vmcnt(0)" ::: "memory");
  barrier_fenced();

#pragma unroll 1
  for (int t = 0; t < NTILES; ++t) {
    const int buf = t & 1, nb = buf ^ 1;
    const bool st = (t + 1 < NTILES);

    // ---- w0: reads ah[0..4)+bh(t) (12); stage Ah(t+1); DEFERRED 16 MFMA
    //      al(t-1) x bhp(t-1). SGB pins 3-read:4-MFMA interleave.
#pragma unroll
    for (int mt = 0; mt < 4; ++mt)
#pragma unroll
      for (int h = 0; h < 2; ++h) ah[mt][h] = LDAh(buf, wm * 4 + mt, h);
#pragma unroll
    for (int nt = 0; nt < 2; ++nt)
#pragma unroll
      for (int h = 0; h < 2; ++h) bh[nt][h] = LDBh(buf, wn * 2 + nt, h);
    if (st) stageAh(nb, t + 1);
    __builtin_amdgcn_s_setprio(1);
#pragma unroll
    for (int h = 0; h < 2; ++h)
#pragma unroll
      for (int mt = 0; mt < 4; ++mt)
#pragma unroll
        for (int nt = 0; nt < 2; ++nt)
          acc[mt][nt] = __builtin_amdgcn_mfma_f32_32x32x16_bf16(al[mt][h], bhp[nt][h], acc[mt][nt], 0, 0, 0);
    __builtin_amdgcn_s_setprio(0);
    __builtin_amdgcn_sched_group_barrier(0x10, 2, 0);   // 2 global_load_lds
#pragma unroll
    for (int g = 0; g < 4; ++g) {
      __builtin_amdgcn_sched_group_barrier(0x100, 3, 0); // 3 ds_read
      __builtin_amdgcn_sched_group_barrier(0x8, 4, 0);   // 4 MFMA
    }
    barrier_fenced();

    // ---- w1: reads bl (4); stage Bh(t+1); 8 MFMA ah[0..2) x bh ----
#pragma unroll
    for (int nt = 0; nt < 2; ++nt)
#pragma unroll
      for (int h = 0; h < 2; ++h) bl[nt][h] = LDBl(buf, wn * 2 + nt, h);
    if (st) stageBh(nb, t + 1);
    __builtin_amdgcn_s_setprio(1);
#pragma unroll
    for (int h = 0; h < 2; ++h)
#pragma unroll
      for (int mt = 0; mt < 2; ++mt)
#pragma unroll
        for (int nt = 0; nt < 2; ++nt)
          acc[mt][nt] = __builtin_amdgcn_mfma_f32_32x32x16_bf16(ah[mt][h], bh[nt][h], acc[mt][nt], 0, 0, 0);
    __builtin_amdgcn_s_setprio(0);
    __builtin_amdgcn_sched_group_barrier(0x10, 2, 0);
#pragma unroll
    for (int g = 0; g < 4; ++g) {
      __builtin_amdgcn_sched_group_barrier(0x100, 1, 0);
      __builtin_amdgcn_sched_group_barrier(0x8, 2, 0);
    }
    barrier_fenced();

    // ---- w2: reads al[0..2) (4); stage Al(t+1); 8 MFMA ah[2..4) x bh ----
#pragma unroll
    for (int mt = 0; mt < 2; ++mt)
#pragma unroll
      for (int h = 0; h < 2; ++h) al[mt][h] = LDAl(buf, wm * 4 + mt, h);
    if (st) stageAl(nb, t + 1);
    __builtin_amdgcn_s_setprio(1);
#pragma unroll
    for (int h = 0; h < 2; ++h)
#pragma unroll
      for (int mt = 2; mt < 4; ++mt)
#pragma unroll
        for (int nt = 0; nt < 2; ++nt)
          acc[mt][nt] = __builtin_amdgcn_mfma_f32_32x32x16_bf16(ah[mt][h], bh[nt][h], acc[mt][nt], 0, 0, 0);
    __builtin_amdgcn_s_setprio(0);
    __builtin_amdgcn_sched_group_barrier(0x10, 2, 0);
#pragma unroll
    for (int g = 0; g < 4; ++g) {
      __builtin_amdgcn_sched_group_barrier(0x100, 1, 0);
      __builtin_amdgcn_sched_group_barrier(0x8, 2, 0);
    }
    barrier_fenced();

    // ---- w3: reads al[2..4) (4); stage Bl(t+1); 8 MFMA ah[0..2) x bl ----
#pragma unroll
    for (int mt = 2; mt < 4; ++mt)
#pragma unroll
      for (int h = 0; h < 2; ++h) al[mt][h] = LDAl(buf, wm * 4 + mt, h);
    if (st) stageBl(nb, t + 1);
    __builtin_amdgcn_s_setprio(1);
#pragma unroll
    for (int h = 0; h < 2; ++h)
#pragma unroll
      for (int mt = 0; mt < 2; ++mt)
#pragma unroll
        for (int nt = 0; nt < 2; ++nt)
          acc[mt][nt] = __builtin_amdgcn_mfma_f32_32x32x16_bf16(ah[mt][h], bl[nt][h], acc[mt][nt], 0, 0, 0);
    __builtin_amdgcn_s_setprio(0);
    __builtin_amdgcn_sched_group_barrier(0x10, 2, 0);
#pragma unroll
    for (int g = 0; g < 4; ++g) {
      __builtin_amdgcn_sched_group_barrier(0x100, 1, 0);
      __builtin_amdgcn_sched_group_barrier(0x8, 2, 0);
    }
    barrier_fenced();

    // ---- w4: 8 MFMA ah[2..4) x bl; save bh -> bhp; boundary drain ----
    __builtin_amdgcn_s_setprio(1);
#pragma unroll
    for (int h = 0; h < 2; ++h)
#pragma unroll
      for (int mt = 2; mt < 4; ++mt)
#pragma unroll
        for (int nt = 0; nt < 2; ++nt)
          acc[mt][nt] = __builtin_amdgcn_mfma_f32_32x32x16_bf16(ah[mt][h], bl[nt][h], acc[mt][nt], 0, 0, 0);
    __builtin_amdgcn_s_setprio(0);
#pragma unroll
    for (int nt = 0; nt < 2; ++nt)
#pragma unroll
      for (int h = 0; h < 2; ++h) bhp[nt][h] = bh[nt][h];

    __builtin_amdgcn_sched_barrier(0);
    asm volatile("s_waitcnt vmcnt(0) lgkmcnt(0)" ::: "memory");
    barrier_fenced();
  }

  // final deferred product: al(31) x bhp(31)
#pragma unroll
  for (int h = 0; h < 2; ++h)
#pragma unroll
    for (int mt = 0; mt < 4; ++mt)
#pragma unroll
      for (int nt = 0; nt < 2; ++nt)
        acc[mt][nt] = __builtin_amdgcn_mfma_f32_32x32x16_bf16(al[mt][h], bhp[nt][h], acc[mt][nt], 0, 0, 0);

  // Epilogue. 32x32 C/D: col = lane&31, row = (reg&3)+8*(reg>>2)+4*(lane>>5).
  const int cm0 = bm + wm * 128;
  const int cn0 = bn + wn * 64;
#pragma unroll
  for (int mt = 0; mt < 4; ++mt)
#pragma unroll
    for (int nt = 0; nt < 2; ++nt) {
      const int col = cn0 + nt * 32 + lr;
      const int row0 = cm0 + mt * 32 + ls * 4;
#pragma unroll
      for (int reg = 0; reg < 16; ++reg) {
        const int row = row0 + (reg & 3) + 8 * (reg >> 2);
        C[(size_t)row * 4096 + col] = acc[mt][nt][reg];
      }
    }
}

// ==================== stage-1: proj (R20-exact, split-K=2) ==================
// Cpart[kh][4096,1024]. 128x128 tile, 8 waves (2x4), wave tile 64x32.
// NBUF=2 -> 64 KB -> 2 blocks/CU. 16 slabs, 2 lockstep windows.
__global__ __launch_bounds__(512, 2)
void gemm_p(const unsigned short* __restrict__ Ah, const unsigned short* __restrict__ Al,
            const unsigned short* __restrict__ Bh, const unsigned short* __restrict__ Bl,
            float* __restrict__ Cpart) {
  constexpr int MT = 4, NT = 2, NTILES = 16;
  __shared__ unsigned short AhS[2][128 * 32];
  __shared__ unsigned short AlS[2][128 * 32];
  __shared__ unsigned short BhS[2][128 * 32];
  __shared__ unsigned short BlS[2][128 * 32];

  const int tid = threadIdx.x;
  const int w = tid >> 6;
  const int lane = tid & 63;
  const int wm = w >> 2, wn = w & 3;
  const int lr = lane & 15;
  const int ls = lane >> 4;

  const int kh = blockIdx.x >> 8;
  const int rid = blockIdx.x & 255;
  const int xcd = rid & 7;
  const int j = rid >> 3;
  const int bm = ((xcd % 4) * 8 + (j % 8)) * 128;
  const int bn = ((xcd / 4) * 4 + (j / 8)) * 128;
  const int koff = kh * 512;
  float* __restrict__ C = Cpart + (size_t)kh * 4096 * 1024;

  const unsigned short *pah, *pal, *pbh, *pbl;
  {
    const size_t ra = (size_t)(bm + w * 16 + lr) * 1024 + koff + ls * 8;
    pah = Ah + ra; pal = Al + ra;
    const size_t rb = (size_t)(bn + w * 16 + lr) * 1024 + koff + ls * 8;
    pbh = Bh + rb; pbl = Bl + rb;
  }

  f32x4 acc[MT][NT] = {};

  auto stage_all = [&](int buf, int t) {
    async_copy_16(&AhS[buf][w * 512], pah + t * 32);
    async_copy_16(&BhS[buf][w * 512], pbh + t * 32);
    async_copy_16(&BlS[buf][w * 512], pbl + t * 32);
    async_copy_16(&AlS[buf][w * 512], pal + t * 32);
  };
  auto LDAh = [&](int buf, int g) { return *(const bf16x8*)&AhS[buf][g * 512 + ls * 128 + lr * 8]; };
  auto LDAl = [&](int buf, int g) { return *(const bf16x8*)&AlS[buf][g * 512 + ls * 128 + lr * 8]; };
  auto LDBh = [&](int buf, int g) { return *(const bf16x8*)&BhS[buf][g * 512 + ls * 128 + lr * 8]; };
  auto LDBl = [&](int buf, int g) { return *(const bf16x8*)&BlS[buf][g * 512 + ls * 128 + lr * 8]; };

  stage_all(0, 0);
  asm volatile("s_waitcnt vmcnt(0)" ::: "memory");
  barrier_fenced();

#pragma unroll 1
  for (int t = 0; t < NTILES; ++t) {
    const int buf = t & 1, nb = buf ^ 1;
    const bool st = (t + 1 < NTILES);
    bf16x8 ah[4], al[4], bh[2], bl[2];

    // w0: Ah,Bh,Bl reads; issue slab t+1; 16 MFMA (ah.bh + ah.bl)
#pragma unroll
    for (int mt = 0; mt < 4; ++mt) ah[mt] = LDAh(buf, wm * MT + mt);
#pragma unroll
    for (int nt = 0; nt < 2; ++nt) bh[nt] = LDBh(buf, wn * NT + nt);
#pragma unroll
    for (int nt = 0; nt < 2; ++nt) bl[nt] = LDBl(buf, wn * NT + nt);
    if (st) stage_all(nb, t + 1);
    barrier_fenced();
    asm volatile("s_waitcnt lgkmcnt(0)" ::: "memory");
    __builtin_amdgcn_sched_barrier(0);
    __builtin_amdgcn_s_setprio(1);
#pragma unroll
    for (int mt = 0; mt < 4; ++mt)
#pragma unroll
      for (int nt = 0; nt < 2; ++nt)
        acc[mt][nt] = __builtin_amdgcn_mfma_f32_16x16x32_bf16(ah[mt], bh[nt], acc[mt][nt], 0, 0, 0);
#pragma unroll
    for (int mt = 0; mt < 4; ++mt)
#pragma unroll
      for (int nt = 0; nt < 2; ++nt)
        acc[mt][nt] = __builtin_amdgcn_mfma_f32_16x16x32_bf16(ah[mt], bl[nt], acc[mt][nt], 0, 0, 0);
    __builtin_amdgcn_s_setprio(0);
    __builtin_amdgcn_sched_barrier(0);

    // w1: Al reads; 8 MFMA (al.bh)
#pragma unroll
    for (int mt = 0; mt < 4; ++mt) al[mt] = LDAl(buf, wm * MT + mt);
    barrier_fenced();
    asm volatile("s_waitcnt lgkmcnt(0)" ::: "memory");
    __builtin_amdgcn_sched_barrier(0);
    __builtin_amdgcn_s_setprio(1);
#pragma unroll
    for (int mt = 0; mt < 4; ++mt)
#pragma unroll
      for (int nt = 0; nt < 2; ++nt)
        acc[mt][nt] = __builtin_amdgcn_mfma_f32_16x16x32_bf16(al[mt], bh[nt], acc[mt][nt], 0, 0, 0);
    __builtin_amdgcn_s_setprio(0);
    __builtin_amdgcn_sched_barrier(0);

    // boundary
    __builtin_amdgcn_sched_barrier(0);
    asm volatile("s_waitcnt vmcnt(0) lgkmcnt(0)" ::: "memory");
    barrier_fenced();
  }

  const int cm0 = bm + wm * 64;
  const int cn0 = bn + wn * 32;
#pragma unroll
  for (int mt = 0; mt < MT; ++mt)
#pragma unroll
    for (int nt = 0; nt < NT; ++nt) {
      const int col = cn0 + nt * 16 + lr;
      const int row0 = cm0 + mt * 16 + ls * 4;
#pragma unroll
      for (int r = 0; r < 4; ++r)
        C[(size_t)(row0 + r) * 1024 + col] = acc[mt][nt][r];
    }
}

// P = Pa + Pb; split hi/lo into Ph, Pl. Row per block.
__global__ __launch_bounds__(256)
void reduce_split(const float* __restrict__ Pa, const float* __restrict__ Pb,
                  unsigned short* __restrict__ Ph, unsigned short* __restrict__ Pl) {
  const size_t row = blockIdx.x;
  const int c4 = threadIdx.x;
  float4 a = ((const float4*)(Pa + row * 1024))[c4];
  float4 b = ((const float4*)(Pb + row * 1024))[c4];
  float s[4] = {a.x + b.x, a.y + b.y, a.z + b.z, a.w + b.w};
  u16x4 h, l;
#pragma unroll
  for (int i = 0; i < 4; ++i) {
    unsigned short hh = f2bf(s[i]);
    h[i] = hh;
    l[i] = f2bf(s[i] - bf2f(hh));
  }
  ((u16x4*)(Ph + row * 1024))[c4] = h;
  ((u16x4*)(Pl + row * 1024))[c4] = l;
}

// In-place row softmax, N=4096, one block per row, 16 floats/thread in regs.
__global__ __launch_bounds__(256)
void softmax_inplace(float* __restrict__ C, int N) {
  float4* r4 = (float4*)(C + (size_t)blockIdx.x * N);
  const int t = threadIdx.x;
  float4 v[4];
  float mx = -3.0e38f;
#pragma unroll
  for (int i = 0; i < 4; ++i) {
    v[i] = r4[t + i * 256];
    mx = fmaxf(mx, fmaxf(fmaxf(v[i].x, v[i].y), fmaxf(v[i].z, v[i].w)));
  }
#pragma unroll
  for (int o = 32; o; o >>= 1) mx = fmaxf(mx, __shfl_xor(mx, o, 64));
  __shared__ float smax[4], ssum[4];
  const int w = t >> 6;
  if ((t & 63) == 0) smax[w] = mx;
  __syncthreads();
  mx = fmaxf(fmaxf(smax[0], smax[1]), fmaxf(smax[2], smax[3]));
  float s = 0.f;
#pragma unroll
  for (int i = 0; i < 4; ++i) {
    v[i].x = __expf(v[i].x - mx);
    v[i].y = __expf(v[i].y - mx);
    v[i].z = __expf(v[i].z - mx);
    v[i].w = __expf(v[i].w - mx);
    s += (v[i].x + v[i].y) + (v[i].z + v[i].w);
  }
#pragma unroll
  for (int o = 32; o; o >>= 1) s += __shfl_xor(s, o, 64);
  if ((t & 63) == 0) ssum[w] = s;
  __syncthreads();
  const float inv = 1.0f / (ssum[0] + ssum[1] + ssum[2] + ssum[3]);
#pragma unroll
  for (int i = 0; i < 4; ++i) {
    v[i].x *= inv; v[i].y *= inv; v[i].z *= inv; v[i].w *= inv;
    r4[t + i * 256] = v[i];
  }
}

extern "C" void kernel_launch(void* const* d_in, const int* in_sizes, int n_in,
                              void* d_out, int out_size, void* d_ws, size_t ws_size,
                              hipStream_t stream) {
  const float* out_state = (const float*)d_in[0];  // [4096,1024]
  const float* history   = (const float*)d_in[1];  // [4096,1024]
  const float* W         = (const float*)d_in[2];  // [1024,1024]
  float* out = (float*)d_out;                      // [4096,4096]

  unsigned short* Hh = (unsigned short*)d_ws;                 // 4096x1024 each
  unsigned short* Hl = Hh + (size_t)4096 * 1024;
  unsigned short* Wh = Hl + (size_t)4096 * 1024;              // 1024x1024
  unsigned short* Wl = Wh + (size_t)1024 * 1024;
  unsigned short* Ah = Wl + (size_t)1024 * 1024;              // 4096x1024
  unsigned short* Al = Ah + (size_t)4096 * 1024;
  unsigned short* Ph = Al + (size_t)4096 * 1024;              // 4096x1024
  unsigned short* Pl = Ph + (size_t)4096 * 1024;
  float* P32 = (float*)(Pl + (size_t)4096 * 1024);            // 2 x 4096x1024 fp32

  split_all<<<9216, 256, 0, stream>>>(history, W, out_state, Hh, Hl, Wh, Wl, Ah, Al);

  // stage-1: split-K=2 proj (R20-exact). 512 blocks, 2 blocks/CU.
  gemm_p<<<512, 512, 0, stream>>>(Hh, Hl, Wh, Wl, P32);
  reduce_split<<<4096, 256, 0, stream>>>(P32, P32 + (size_t)4096 * 1024, Ph, Pl);

  // stage-2: energies, 32x32x16 MFMA, deferred-product + SGB interleave.
  gemm_e<<<256, 512, 0, stream>>>(Ah, Al, Ph, Pl, out);

  softmax_inplace<<<4096, 256, 0, stream>>>(out, 4096);
}